// Round 9
// baseline (222.050 us; speedup 1.0000x reference)
//
#include <hip/hip_runtime.h>

#define EPS_DIST 1e-10f
#define BN_EPS 1e-5f

typedef short short8 __attribute__((ext_vector_type(8)));
typedef float floatx4 __attribute__((ext_vector_type(4)));

__device__ __forceinline__ unsigned short f2bf(float f) {
  unsigned u = __float_as_uint(f);
  unsigned r = (u + 0x7FFFu + ((u >> 16) & 1u)) >> 16;  // RNE
  return (unsigned short)r;
}
__device__ __forceinline__ float bf2f(unsigned short h) {
  return __uint_as_float(((unsigned)h) << 16);
}

// direct global->LDS async copy, 16B per lane. LDS dest must be
// wave-uniform-base + lane*16 (our staging layouts are exactly that).
__device__ __forceinline__ void gload16(const void* g, void* l) {
  __builtin_amdgcn_global_load_lds(
      (const __attribute__((address_space(1))) unsigned int*)g,
      (__attribute__((address_space(3))) unsigned int*)l, 16, 0, 0);
}

// ------- tcvt_all: 1D grid 3136.
//   id<1024:  points2 fp32[B][256][1024] -> Xt2 bf16[B][1024][256]
//   id<3072:  points1 fp32[B][128][4096] -> Xt1 bf16[B][4096][128]
//   else:     W0 ++ W1 -> Wb bf16
__global__ __launch_bounds__(256) void tcvt_all_kernel(
    const float* __restrict__ p2, unsigned short* __restrict__ Xt2,
    const float* __restrict__ p1, unsigned short* __restrict__ Xt1,
    const float* __restrict__ W0, const float* __restrict__ W1,
    unsigned short* __restrict__ Wb) {
  const int tid = threadIdx.x;
  const int id = blockIdx.x;
  if (id >= 3072) {  // cvt_w: 64 blocks x 2048 elems = 131072
    int base = (id - 3072) * 2048 + tid;
#pragma unroll
    for (int p = 0; p < 8; ++p) {
      int i = base + p * 256;
      float v = (i < 98304) ? W0[i] : W1[i - 98304];
      Wb[i] = f2bf(v);
    }
    return;
  }
  __shared__ float sm[64][65];
  const float* src; unsigned short* dst; int K, N, n0, k0, b;
  if (id < 1024) {
    src = p2; dst = Xt2; K = 256; N = 1024;
    n0 = (id & 15) * 64; k0 = ((id >> 4) & 3) * 64; b = id >> 6;
  } else {
    int q = id - 1024;
    src = p1; dst = Xt1; K = 128; N = 4096;
    n0 = (q & 63) * 64; k0 = ((q >> 6) & 1) * 64; b = q >> 7;
  }
  const int nl = tid & 63, kq = tid >> 6;
  const float* s = src + ((size_t)b * K + k0) * N + n0;
#pragma unroll
  for (int p = 0; p < 16; ++p) {
    int kl = p * 4 + kq;
    sm[kl][nl] = s[(size_t)kl * N + nl];
  }
  __syncthreads();
#pragma unroll
  for (int p = 0; p < 2; ++p) {
    int c = p * 256 + tid;
    int rn = c >> 3, jj = c & 7;
    short8 v;
#pragma unroll
    for (int u = 0; u < 8; ++u) v[u] = (short)f2bf(sm[jj * 8 + u][rn]);
    *(short8*)(dst + (size_t)(b * N + n0 + rn) * K + k0 + jj * 8) = v;
  }
}

// ---- knni: fused 3-NN + interp of RAW x2 features.
// Phase 1 sorted top-3 insert per candidate:
//   values:  e0'=min(e0,d); e1'=med3(e0,d,e1); e2'=med3(e1,d,e2)  (3 f32 instr)
//   indices: 3 strict-< cmps + 5 cndmasks (ties keep incumbent = smaller j,
//            j ascends per lane -> exactly lax.top_k stable order)
// Phase 2: Xi[n][:] = sum_k w_k * Xt2[idx_k][:], one wave per n (full 512B row).
// 1D grid 2048, XCD-swizzled (2 batches/XCD, Xt2 L2-resident).
__global__ __launch_bounds__(256) void knni_kernel(
    const float* __restrict__ xyz1, const float* __restrict__ xyz2,
    const unsigned short* __restrict__ Xt2, unsigned short* __restrict__ Xi) {
  __shared__ float4 s2[1024];  // x,y,z,|.|^2
  __shared__ int sidx[96];
  __shared__ float swgt[96];
  const int lin = blockIdx.x;
  const int xcd = lin & 7;
  const int slot = lin >> 3;            // 0..255
  const int b = xcd * 2 + (slot >> 7);  // 2 batches per XCD
  const int qtile = slot & 127;
  const int tid = threadIdx.x;
  const float* x2 = xyz2 + b * 3072;
  for (int j = tid; j < 1024; j += 256) {
    float x = x2[j * 3 + 0], y = x2[j * 3 + 1], z = x2[j * 3 + 2];
    s2[j] = make_float4(x, y, z, (x * x + y * y) + z * z);
  }
  __syncthreads();
  const int q = tid >> 3, sub = tid & 7;
  const int n = qtile * 32 + q;
  const float* p1 = xyz1 + (b * 4096 + n) * 3;
  const float ax = p1[0], ay = p1[1], az = p1[2];
  const float s1 = (ax * ax + ay * ay) + az * az;
  float d0 = 3.4e38f, d1 = 3.4e38f, d2 = 3.4e38f;
  int i0 = 0x7fffffff, i1 = 0x7fffffff, i2 = 0x7fffffff;
#pragma unroll 8
  for (int jj = 0; jj < 128; ++jj) {
    int j = jj * 8 + sub;
    float4 c = s2[j];
    float dot = (ax * c.x + ay * c.y) + az * c.z;
    float d = fmaxf((s1 + c.w) - 2.0f * dot, EPS_DIST);
    bool c0 = d < d0, c1 = d < d1, c2 = d < d2;
    int ni0 = c0 ? j : i0;
    int ni1 = c0 ? i0 : (c1 ? j : i1);
    int ni2 = c1 ? i1 : (c2 ? j : i2);
    float nd0 = fminf(d0, d);
    float nd1 = __builtin_amdgcn_fmed3f(d0, d, d1);
    float nd2 = __builtin_amdgcn_fmed3f(d1, d, d2);
    d0 = nd0; d1 = nd1; d2 = nd2;
    i0 = ni0; i1 = ni1; i2 = ni2;
  }
  // butterfly merge of sorted (d,idx) triples; lexicographic == lax.top_k order
#pragma unroll
  for (int m = 1; m <= 4; m <<= 1) {
    float e0 = __shfl_xor(d0, m), e1 = __shfl_xor(d1, m), e2 = __shfl_xor(d2, m);
    int   f0 = __shfl_xor(i0, m), f1 = __shfl_xor(i1, m), f2 = __shfl_xor(i2, m);
    float A[3] = {d0, d1, d2}, Bv[3] = {e0, e1, e2};
    int   I[3] = {i0, i1, i2}, J[3] = {f0, f1, f2};
    float md[3]; int mi[3];
    int pa = 0, pb = 0;
#pragma unroll
    for (int k = 0; k < 3; ++k) {
      float da = A[pa], db = Bv[pb];
      int ia = I[pa], ib = J[pb];
      bool ta = (da < db) || (da == db && ia < ib);
      md[k] = ta ? da : db; mi[k] = ta ? ia : ib;
      pa += ta ? 1 : 0; pb += ta ? 0 : 1;
    }
    d0 = md[0]; d1 = md[1]; d2 = md[2];
    i0 = mi[0]; i1 = mi[1]; i2 = mi[2];
  }
  if (sub == 0) {
    float w0 = 1.0f / d0, w1 = 1.0f / d1, w2 = 1.0f / d2;
    float s = (w0 + w1) + w2;
    sidx[q * 3 + 0] = i0; sidx[q * 3 + 1] = i1; sidx[q * 3 + 2] = i2;
    swgt[q * 3 + 0] = w0 / s; swgt[q * 3 + 1] = w1 / s; swgt[q * 3 + 2] = w2 / s;
  }
  __syncthreads();
  // ---- phase 2: interp raw x2 feature rows for the block's 32 queries ----
  const int w = tid >> 6, lane = tid & 63;
  const unsigned short* zb = Xt2 + (size_t)b * 1024 * 256;
#pragma unroll
  for (int t = 0; t < 8; ++t) {
    int nl = w * 8 + t;                  // 0..31, wave-uniform
    int nn = qtile * 32 + nl;
    int g0 = sidx[nl * 3 + 0], g1 = sidx[nl * 3 + 1], g2 = sidx[nl * 3 + 2];
    float w0 = swgt[nl * 3 + 0], w1 = swgt[nl * 3 + 1], w2 = swgt[nl * 3 + 2];
    ushort4 r0 = *(const ushort4*)(zb + (size_t)g0 * 256 + lane * 4);
    ushort4 r1 = *(const ushort4*)(zb + (size_t)g1 * 256 + lane * 4);
    ushort4 r2 = *(const ushort4*)(zb + (size_t)g2 * 256 + lane * 4);
    ushort4 o;
    o.x = f2bf(w0 * bf2f(r0.x) + w1 * bf2f(r1.x) + w2 * bf2f(r2.x));
    o.y = f2bf(w0 * bf2f(r0.y) + w1 * bf2f(r1.y) + w2 * bf2f(r2.y));
    o.z = f2bf(w0 * bf2f(r0.z) + w1 * bf2f(r1.z) + w2 * bf2f(r2.z));
    o.w = f2bf(w0 * bf2f(r0.w) + w1 * bf2f(r1.w) + w2 * bf2f(r2.w));
    *(ushort4*)(Xi + ((size_t)b * 4096 + nn) * 256 + lane * 4) = o;
  }
}

// -- gemm0 (+fused stats0): y0t = W0b * concat(Xt1, Xi) + b0.  K=384 (12 steps),
//    o-tile 128, n-tile 128; 1D grid 1024, XCD-swizzled; dbuf gload_lds pipeline.
//    Stats: shfl-reduce over l15, atomics only from lane0-of-16 (<=2-way);
//    global partials per-XCD (acc0x[xcd][512]) to cut same-address chains 8x. --
__global__ __launch_bounds__(256) void gemm0_kernel(
    const unsigned short* __restrict__ Wb, const unsigned short* __restrict__ Xt1,
    const unsigned short* __restrict__ Xi, const float* __restrict__ b0,
    unsigned short* __restrict__ y0t, float* __restrict__ acc0x) {
  __shared__ short sA[2][128 * 32];   // 128 o-rows x 32 k
  __shared__ short sB[2][128 * 32];   // 128 n-rows x 32 k
  __shared__ float ls[256];           // s[128] | ss[128] per local o
  const int lin = blockIdx.x;
  const int xcd = lin & 7;
  const int slot = lin >> 3;            // 0..127
  const int b = xcd * 2 + (slot >> 6);  // 2 batches per XCD
  const int inner = slot & 63;          // 64 blocks per batch
  const int o0 = (inner & 1) * 128;     // 2 o-tiles
  const int n0 = (inner >> 1) * 128;    // 32 n-tiles
  const int tid = threadIdx.x, lane = tid & 63, w = tid >> 6;
  const int wo = w >> 1, wn = w & 1, quad = lane >> 4, l15 = lane & 15;
  const int c0 = tid, c1 = 256 + tid;
  const int r0 = c0 >> 2, j0 = c0 & 3, r1 = c1 >> 2, j1 = c1 & 3;
  const unsigned short* xb = Xt1 + (size_t)(b * 4096 + n0) * 128;
  const unsigned short* xi = Xi + (size_t)(b * 4096 + n0) * 256;
  ls[tid] = 0.f;
  auto STAGE = [&](int h, int kb) {
    gload16(Wb + (size_t)(o0 + r0) * 384 + kb + j0 * 8, &sA[h][c0 * 8]);
    gload16(Wb + (size_t)(o0 + r1) * 384 + kb + j1 * 8, &sA[h][c1 * 8]);
    if (kb < 128) {
      gload16(xb + (size_t)r0 * 128 + kb + j0 * 8, &sB[h][c0 * 8]);
      gload16(xb + (size_t)r1 * 128 + kb + j1 * 8, &sB[h][c1 * 8]);
    } else {
      gload16(xi + (size_t)r0 * 256 + (kb - 128) + j0 * 8, &sB[h][c0 * 8]);
      gload16(xi + (size_t)r1 * 256 + (kb - 128) + j1 * 8, &sB[h][c1 * 8]);
    }
  };
  floatx4 acc[4][4] = {};
  STAGE(0, 0);
  asm volatile("s_waitcnt vmcnt(0)" ::: "memory");
  __syncthreads();
  int cur = 0;
  for (int t = 0; t < 12; ++t) {
    if (t < 11) STAGE(cur ^ 1, (t + 1) * 32);
    short8 av[4], bv[4];
#pragma unroll
    for (int i = 0; i < 4; ++i)
      av[i] = *(const short8*)(&sA[cur][(wo * 64 + i * 16 + l15) * 32 + quad * 8]);
#pragma unroll
    for (int j = 0; j < 4; ++j)
      bv[j] = *(const short8*)(&sB[cur][(wn * 64 + j * 16 + l15) * 32 + quad * 8]);
#pragma unroll
    for (int i = 0; i < 4; ++i)
#pragma unroll
      for (int j = 0; j < 4; ++j)
        acc[i][j] = __builtin_amdgcn_mfma_f32_16x16x32_bf16(av[i], bv[j], acc[i][j], 0, 0, 0);
    if (t < 11) {
      asm volatile("s_waitcnt vmcnt(0)" ::: "memory");
      __syncthreads();
      cur ^= 1;
    }
  }
#pragma unroll
  for (int i = 0; i < 4; ++i) {
    int obg = o0 + wo * 64 + i * 16 + quad * 4;   // global o
    floatx4 bias = *(const floatx4*)(b0 + obg);
    float ps[4] = {0.f, 0.f, 0.f, 0.f}, pq[4] = {0.f, 0.f, 0.f, 0.f};
#pragma unroll
    for (int j = 0; j < 4; ++j) {
      int n = n0 + wn * 64 + j * 16 + l15;
      ushort4 out;
      out.x = f2bf(acc[i][j][0] + bias[0]);
      out.y = f2bf(acc[i][j][1] + bias[1]);
      out.z = f2bf(acc[i][j][2] + bias[2]);
      out.w = f2bf(acc[i][j][3] + bias[3]);
      *(ushort4*)(y0t + (size_t)(b * 4096 + n) * 256 + obg) = out;
      // stats on the ROUNDED values (self-consistent with what gemm1 reads)
      float q0 = bf2f(out.x), q1 = bf2f(out.y), q2 = bf2f(out.z), q3 = bf2f(out.w);
      ps[0] += q0; ps[1] += q1; ps[2] += q2; ps[3] += q3;
      pq[0] += q0 * q0; pq[1] += q1 * q1; pq[2] += q2 * q2; pq[3] += q3 * q3;
    }
    // reduce across the 16 l15 lanes (same obg within a quad), then one
    // atomic per quad (<=2-way contention: 2 waves share each o-range)
#pragma unroll
    for (int m = 1; m <= 8; m <<= 1) {
#pragma unroll
      for (int u = 0; u < 4; ++u) {
        ps[u] += __shfl_xor(ps[u], m);
        pq[u] += __shfl_xor(pq[u], m);
      }
    }
    if (l15 == 0) {
      int lo = obg - o0;
#pragma unroll
      for (int u = 0; u < 4; ++u) {
        atomicAdd(&ls[lo + u], ps[u]);
        atomicAdd(&ls[128 + lo + u], pq[u]);
      }
    }
  }
  __syncthreads();
  if (tid < 128) {
    atomicAdd(&acc0x[xcd * 512 + o0 + tid], ls[tid]);
    atomicAdd(&acc0x[xcd * 512 + 256 + o0 + tid], ls[128 + tid]);
  }
}

// ---- gemm1 (BN+ReLU fused on A-load, fused stats1, finalize0 folded into
//      prologue summing per-XCD partials): y1 = W1b*relu(bn(y0t))^T + b1. ----
__global__ __launch_bounds__(256) void gemm1_kernel(
    const unsigned short* __restrict__ Wb, const unsigned short* __restrict__ y0t,
    const float* __restrict__ acc0x, const float* __restrict__ g0,
    const float* __restrict__ be0, const float* __restrict__ b1,
    float* __restrict__ y1, float* __restrict__ acc1x) {
  __shared__ short sA[2][128 * 32];   // 128 n-rows x 32 k  (BN+ReLU'd x1)
  __shared__ short sB[2][128 * 32];   // 128 o-rows x 32 k
  __shared__ float sst[512];          // scale[256] | offset[256]
  __shared__ float ls[256];           // s[128] | ss[128]
  const int lin = blockIdx.x;
  const int xcd = lin & 7;
  const int slot = lin >> 3;            // 0..63
  const int b = xcd * 2 + (slot >> 5);  // 2 batches per XCD (matches gemm0)
  const int n0 = (slot & 31) * 128;     // 32 n-tiles
  const int tid = threadIdx.x, lane = tid & 63, w = tid >> 6;
  const int wm = w & 1, wo2 = w >> 1, quad = lane >> 4, l15 = lane & 15;
  const unsigned short* W1b = Wb + 98304;
  const int c0 = tid, c1 = 256 + tid;
  const int r0 = c0 >> 2, j0 = c0 & 3, r1 = c1 >> 2, j1 = c1 & 3;
  const unsigned short* yb = y0t + (size_t)(b * 4096 + n0) * 256;
  short8 ra0, ra1;
  auto LOADRAW = [&](int kb) {
    ra0 = *(const short8*)(yb + (size_t)r0 * 256 + kb + j0 * 8);
    ra1 = *(const short8*)(yb + (size_t)r1 * 256 + kb + j1 * 8);
  };
  auto XFORM = [&](int h, int kb) {
    int k0b = kb + j0 * 8, k1b = kb + j1 * 8;
    short8 v0, v1;
#pragma unroll
    for (int u = 0; u < 8; ++u) {
      float t0 = fmaxf(bf2f((unsigned short)ra0[u]) * sst[k0b + u] + sst[256 + k0b + u], 0.f);
      float t1 = fmaxf(bf2f((unsigned short)ra1[u]) * sst[k1b + u] + sst[256 + k1b + u], 0.f);
      v0[u] = (short)f2bf(t0);
      v1[u] = (short)f2bf(t1);
    }
    *(short8*)(&sA[h][c0 * 8]) = v0;
    *(short8*)(&sA[h][c1 * 8]) = v1;
  };
  auto STAGEB = [&](int h, int kb) {
    gload16(W1b + (size_t)r0 * 256 + kb + j0 * 8, &sB[h][c0 * 8]);
    gload16(W1b + (size_t)r1 * 256 + kb + j1 * 8, &sB[h][c1 * 8]);
  };
  LOADRAW(0);
  {  // finalize0 folded: sum per-XCD partials, derive BN scale/offset
    const float inv = 1.0f / 65536.0f;
    float s0 = 0.f, s1 = 0.f;
#pragma unroll
    for (int x = 0; x < 8; ++x) {
      s0 += acc0x[x * 512 + tid];
      s1 += acc0x[x * 512 + 256 + tid];
    }
    float mean = s0 * inv;
    float var = s1 * inv - mean * mean;
    float sc = g0[tid] / sqrtf(var + BN_EPS);
    sst[tid] = sc;
    sst[256 + tid] = be0[tid] - mean * sc;
  }
  ls[tid] = 0.f;
  __syncthreads();                     // sst visible to all
  XFORM(0, 0);
  STAGEB(0, 0);
  asm volatile("s_waitcnt vmcnt(0)" ::: "memory");
  __syncthreads();
  floatx4 acc[4][4] = {};
  int cur = 0;
  for (int t = 0; t < 8; ++t) {
    if (t < 7) {
      LOADRAW((t + 1) * 32);
      STAGEB(cur ^ 1, (t + 1) * 32);
    }
    short8 av[4], bv[4];
#pragma unroll
    for (int i = 0; i < 4; ++i)
      av[i] = *(const short8*)(&sA[cur][(wm * 64 + i * 16 + l15) * 32 + quad * 8]);
#pragma unroll
    for (int j = 0; j < 4; ++j)
      bv[j] = *(const short8*)(&sB[cur][(wo2 * 64 + j * 16 + l15) * 32 + quad * 8]);
#pragma unroll
    for (int i = 0; i < 4; ++i)
#pragma unroll
      for (int j = 0; j < 4; ++j)
        acc[i][j] = __builtin_amdgcn_mfma_f32_16x16x32_bf16(av[i], bv[j], acc[i][j], 0, 0, 0);
    if (t < 7) {
      XFORM(cur ^ 1, (t + 1) * 32);
      asm volatile("s_waitcnt vmcnt(0)" ::: "memory");
      __syncthreads();
      cur ^= 1;
    }
  }
#pragma unroll
  for (int j = 0; j < 4; ++j) {
    int o = wo2 * 64 + j * 16 + l15;
    float bias = b1[o];
    float s = 0.f, q = 0.f;
#pragma unroll
    for (int i = 0; i < 4; ++i) {
      int n = n0 + wm * 64 + i * 16 + quad * 4;
      floatx4 v = acc[i][j] + bias;
      *(floatx4*)(y1 + (size_t)(b * 128 + o) * 4096 + n) = v;
      s += (v[0] + v[1]) + (v[2] + v[3]);
      q += (v[0] * v[0] + v[1] * v[1]) + (v[2] * v[2] + v[3] * v[3]);
    }
    // reduce over the 4 quads (lanes sharing o) then single-lane atomics
    s += __shfl_xor(s, 16); s += __shfl_xor(s, 32);
    q += __shfl_xor(q, 16); q += __shfl_xor(q, 32);
    if (quad == 0) {
      atomicAdd(&ls[o], s);
      atomicAdd(&ls[128 + o], q);
    }
  }
  __syncthreads();
  if (tid < 128) {
    atomicAdd(&acc1x[xcd * 256 + tid], ls[tid]);
    atomicAdd(&acc1x[xcd * 256 + 128 + tid], ls[128 + tid]);
  }
}

// ---------------- bnrelu_f: fp32 in place on d_out, float4/thread ----------------
// finalize1 folded: o is block-uniform; sums per-XCD partials inline.
// grid 8192 x 256
__global__ __launch_bounds__(256) void bnrelu_f_kernel(
    float* __restrict__ y, const float* __restrict__ acc1x,
    const float* __restrict__ g1, const float* __restrict__ be1) {
  size_t i4 = (size_t)blockIdx.x * 256 + threadIdx.x;
  int o = (int)(blockIdx.x >> 2) & 127;   // block covers 1024 floats within one o
  const float inv = 1.0f / 65536.0f;
  float s0 = 0.f, s1 = 0.f;
#pragma unroll
  for (int x = 0; x < 8; ++x) {
    s0 += acc1x[x * 256 + o];
    s1 += acc1x[x * 256 + 128 + o];
  }
  float m = s0 * inv;
  float var = s1 * inv - m * m;
  float sc = g1[o] / sqrtf(var + BN_EPS);
  float bb = be1[o];
  floatx4 v = ((floatx4*)y)[i4];
  floatx4 r;
  r[0] = fmaxf((v[0] - m) * sc + bb, 0.f);
  r[1] = fmaxf((v[1] - m) * sc + bb, 0.f);
  r[2] = fmaxf((v[2] - m) * sc + bb, 0.f);
  r[3] = fmaxf((v[3] - m) * sc + bb, 0.f);
  ((floatx4*)y)[i4] = r;
}

extern "C" void kernel_launch(void* const* d_in, const int* in_sizes, int n_in,
                              void* d_out, int out_size, void* d_ws, size_t ws_size,
                              hipStream_t stream) {
  (void)in_sizes; (void)n_in; (void)out_size; (void)ws_size;
  const float* xyz1    = (const float*)d_in[0];
  const float* xyz2    = (const float*)d_in[1];
  const float* points1 = (const float*)d_in[2];
  const float* points2 = (const float*)d_in[3];
  const float* W0  = (const float*)d_in[4];
  const float* b0  = (const float*)d_in[5];
  const float* g0  = (const float*)d_in[6];
  const float* be0 = (const float*)d_in[7];
  const float* W1  = (const float*)d_in[8];
  const float* b1  = (const float*)d_in[9];
  const float* g1  = (const float*)d_in[10];
  const float* be1 = (const float*)d_in[11];

  char* ws = (char*)d_ws;
  // layout (bytes):
  //   [0,        16K)    acc0x f32[8][512]  } per-XCD stat partials,
  //   [16K,      24K)    acc1x f32[8][256]  } zeroed by one 24576B memset
  //   [1581056,  +256K)  Wb   bf16 (W0b 98304 ++ W1b 32768)
  //   [2M,       10M)    Xt2  bf16 (B,1024,256)
  //   [10M,      26M)    Xt1  bf16 (B,4096,128)
  //   [26M,      58M)    y0t  bf16 (B,4096,256)  -- pre-BN y0 (BN fused in gemm1)
  // Xi bf16 (B,4096,256) = 32 MB lives in d_out; dead before gemm1 writes y1.
  float* acc0x = (float*)(ws + 0);
  float* acc1x = (float*)(ws + 16384);
  unsigned short* Wb  = (unsigned short*)(ws + 1581056);
  unsigned short* Xt2 = (unsigned short*)(ws + 2097152);
  unsigned short* Xt1 = (unsigned short*)(ws + 10485760);
  unsigned short* y0t = (unsigned short*)(ws + 27262976);
  unsigned short* Xi = (unsigned short*)d_out;
  float* y1 = (float*)d_out;

  hipMemsetAsync(acc0x, 0, 24576, stream);
  tcvt_all_kernel<<<3136, 256, 0, stream>>>(points2, Xt2, points1, Xt1, W0, W1, Wb);
  knni_kernel<<<2048, 256, 0, stream>>>(xyz1, xyz2, Xt2, Xi);
  gemm0_kernel<<<1024, 256, 0, stream>>>(Wb, Xt1, Xi, b0, y0t, acc0x);
  gemm1_kernel<<<512, 256, 0, stream>>>(Wb, y0t, acc0x, g0, be0, b1, y1, acc1x);
  bnrelu_f_kernel<<<8192, 256, 0, stream>>>(y1, acc1x, g1, be1);
}

// Round 14
// 216.981 us; speedup vs baseline: 1.0234x; 1.0234x over previous
//
#include <hip/hip_runtime.h>

#define EPS_DIST 1e-10f
#define BN_EPS 1e-5f

typedef short short8 __attribute__((ext_vector_type(8)));
typedef float floatx4 __attribute__((ext_vector_type(4)));

__device__ __forceinline__ unsigned short f2bf(float f) {
  unsigned u = __float_as_uint(f);
  unsigned r = (u + 0x7FFFu + ((u >> 16) & 1u)) >> 16;  // RNE
  return (unsigned short)r;
}
__device__ __forceinline__ float bf2f(unsigned short h) {
  return __uint_as_float(((unsigned)h) << 16);
}

// direct global->LDS async copy, 16B per lane. LDS dest must be
// wave-uniform-base + lane*16 (our staging layouts are exactly that).
__device__ __forceinline__ void gload16(const void* g, void* l) {
  __builtin_amdgcn_global_load_lds(
      (const __attribute__((address_space(1))) unsigned int*)g,
      (__attribute__((address_space(3))) unsigned int*)l, 16, 0, 0);
}

// ------- tcvt_all: 1D grid 3136.
//   id<1024:  points2 fp32[B][256][1024] -> Xt2 bf16[B][1024][256]
//   id<3072:  points1 fp32[B][128][4096] -> Xt1 bf16[B][4096][128]
//   else:     W0 ++ W1 -> Wb bf16
__global__ __launch_bounds__(256) void tcvt_all_kernel(
    const float* __restrict__ p2, unsigned short* __restrict__ Xt2,
    const float* __restrict__ p1, unsigned short* __restrict__ Xt1,
    const float* __restrict__ W0, const float* __restrict__ W1,
    unsigned short* __restrict__ Wb) {
  const int tid = threadIdx.x;
  const int id = blockIdx.x;
  if (id >= 3072) {  // cvt_w: 64 blocks x 2048 elems = 131072
    int base = (id - 3072) * 2048 + tid;
#pragma unroll
    for (int p = 0; p < 8; ++p) {
      int i = base + p * 256;
      float v = (i < 98304) ? W0[i] : W1[i - 98304];
      Wb[i] = f2bf(v);
    }
    return;
  }
  __shared__ float sm[64][65];
  const float* src; unsigned short* dst; int K, N, n0, k0, b;
  if (id < 1024) {
    src = p2; dst = Xt2; K = 256; N = 1024;
    n0 = (id & 15) * 64; k0 = ((id >> 4) & 3) * 64; b = id >> 6;
  } else {
    int q = id - 1024;
    src = p1; dst = Xt1; K = 128; N = 4096;
    n0 = (q & 63) * 64; k0 = ((q >> 6) & 1) * 64; b = q >> 7;
  }
  const int nl = tid & 63, kq = tid >> 6;
  const float* s = src + ((size_t)b * K + k0) * N + n0;
#pragma unroll
  for (int p = 0; p < 16; ++p) {
    int kl = p * 4 + kq;
    sm[kl][nl] = s[(size_t)kl * N + nl];
  }
  __syncthreads();
#pragma unroll
  for (int p = 0; p < 2; ++p) {
    int c = p * 256 + tid;
    int rn = c >> 3, jj = c & 7;
    short8 v;
#pragma unroll
    for (int u = 0; u < 8; ++u) v[u] = (short)f2bf(sm[jj * 8 + u][rn]);
    *(short8*)(dst + (size_t)(b * N + n0 + rn) * K + k0 + jj * 8) = v;
  }
}

// ---- knni: fused 3-NN + interp of RAW x2 features.
// Phase 1 sorted top-3 insert per candidate (round-9 exact distance form):
//   values:  e0'=min(e0,d); e1'=med3(e0,d,e1); e2'=med3(e1,d,e2)  (3 f32 instr)
//   indices: 3 strict-< cmps + 5 cndmasks (ties keep incumbent = smaller j,
//            j ascends per lane -> exactly lax.top_k stable order)
// Phase 2: Xi[n][:] = sum_k w_k * Xt2[idx_k][:], one wave per n (full 512B row).
// 1D grid 2048, XCD-swizzled (2 batches/XCD, Xt2 L2-resident).
__global__ __launch_bounds__(256) void knni_kernel(
    const float* __restrict__ xyz1, const float* __restrict__ xyz2,
    const unsigned short* __restrict__ Xt2, unsigned short* __restrict__ Xi) {
  __shared__ float4 s2[1024];  // x,y,z,|.|^2
  __shared__ int sidx[96];
  __shared__ float swgt[96];
  const int lin = blockIdx.x;
  const int xcd = lin & 7;
  const int slot = lin >> 3;            // 0..255
  const int b = xcd * 2 + (slot >> 7);  // 2 batches per XCD
  const int qtile = slot & 127;
  const int tid = threadIdx.x;
  const float* x2 = xyz2 + b * 3072;
  for (int j = tid; j < 1024; j += 256) {
    float x = x2[j * 3 + 0], y = x2[j * 3 + 1], z = x2[j * 3 + 2];
    s2[j] = make_float4(x, y, z, (x * x + y * y) + z * z);
  }
  __syncthreads();
  const int q = tid >> 3, sub = tid & 7;
  const int n = qtile * 32 + q;
  const float* p1 = xyz1 + (b * 4096 + n) * 3;
  const float ax = p1[0], ay = p1[1], az = p1[2];
  const float s1 = (ax * ax + ay * ay) + az * az;
  float d0 = 3.4e38f, d1 = 3.4e38f, d2 = 3.4e38f;
  int i0 = 0x7fffffff, i1 = 0x7fffffff, i2 = 0x7fffffff;
#pragma unroll 8
  for (int jj = 0; jj < 128; ++jj) {
    int j = jj * 8 + sub;
    float4 c = s2[j];
    float dot = (ax * c.x + ay * c.y) + az * c.z;
    float d = fmaxf((s1 + c.w) - 2.0f * dot, EPS_DIST);
    bool c0 = d < d0, c1 = d < d1, c2 = d < d2;
    int ni0 = c0 ? j : i0;
    int ni1 = c0 ? i0 : (c1 ? j : i1);
    int ni2 = c1 ? i1 : (c2 ? j : i2);
    float nd0 = fminf(d0, d);
    float nd1 = __builtin_amdgcn_fmed3f(d0, d, d1);
    float nd2 = __builtin_amdgcn_fmed3f(d1, d, d2);
    d0 = nd0; d1 = nd1; d2 = nd2;
    i0 = ni0; i1 = ni1; i2 = ni2;
  }
  // butterfly merge of sorted (d,idx) triples; lexicographic == lax.top_k order
#pragma unroll
  for (int m = 1; m <= 4; m <<= 1) {
    float e0 = __shfl_xor(d0, m), e1 = __shfl_xor(d1, m), e2 = __shfl_xor(d2, m);
    int   f0 = __shfl_xor(i0, m), f1 = __shfl_xor(i1, m), f2 = __shfl_xor(i2, m);
    float A[3] = {d0, d1, d2}, Bv[3] = {e0, e1, e2};
    int   I[3] = {i0, i1, i2}, J[3] = {f0, f1, f2};
    float md[3]; int mi[3];
    int pa = 0, pb = 0;
#pragma unroll
    for (int k = 0; k < 3; ++k) {
      float da = A[pa], db = Bv[pb];
      int ia = I[pa], ib = J[pb];
      bool ta = (da < db) || (da == db && ia < ib);
      md[k] = ta ? da : db; mi[k] = ta ? ia : ib;
      pa += ta ? 1 : 0; pb += ta ? 0 : 1;
    }
    d0 = md[0]; d1 = md[1]; d2 = md[2];
    i0 = mi[0]; i1 = mi[1]; i2 = mi[2];
  }
  if (sub == 0) {
    float w0 = 1.0f / d0, w1 = 1.0f / d1, w2 = 1.0f / d2;
    float s = (w0 + w1) + w2;
    sidx[q * 3 + 0] = i0; sidx[q * 3 + 1] = i1; sidx[q * 3 + 2] = i2;
    swgt[q * 3 + 0] = w0 / s; swgt[q * 3 + 1] = w1 / s; swgt[q * 3 + 2] = w2 / s;
  }
  __syncthreads();
  // ---- phase 2: interp raw x2 feature rows for the block's 32 queries ----
  const int w = tid >> 6, lane = tid & 63;
  const unsigned short* zb = Xt2 + (size_t)b * 1024 * 256;
#pragma unroll
  for (int t = 0; t < 8; ++t) {
    int nl = w * 8 + t;                  // 0..31, wave-uniform
    int nn = qtile * 32 + nl;
    int g0 = sidx[nl * 3 + 0], g1 = sidx[nl * 3 + 1], g2 = sidx[nl * 3 + 2];
    float w0 = swgt[nl * 3 + 0], w1 = swgt[nl * 3 + 1], w2 = swgt[nl * 3 + 2];
    ushort4 r0 = *(const ushort4*)(zb + (size_t)g0 * 256 + lane * 4);
    ushort4 r1 = *(const ushort4*)(zb + (size_t)g1 * 256 + lane * 4);
    ushort4 r2 = *(const ushort4*)(zb + (size_t)g2 * 256 + lane * 4);
    ushort4 o;
    o.x = f2bf(w0 * bf2f(r0.x) + w1 * bf2f(r1.x) + w2 * bf2f(r2.x));
    o.y = f2bf(w0 * bf2f(r0.y) + w1 * bf2f(r1.y) + w2 * bf2f(r2.y));
    o.z = f2bf(w0 * bf2f(r0.z) + w1 * bf2f(r1.z) + w2 * bf2f(r2.z));
    o.w = f2bf(w0 * bf2f(r0.w) + w1 * bf2f(r1.w) + w2 * bf2f(r2.w));
    *(ushort4*)(Xi + ((size_t)b * 4096 + nn) * 256 + lane * 4) = o;
  }
}

// -- gemm0 (+fused stats0): y0t = W0b * concat(Xt1, Xi) + b0.  K=384 (12 steps).
//    3-buffer, 2-ahead counted-vmcnt pipeline (T4): raw s_barrier, vmcnt(4) at
//    step head (only next step's 4 loads in flight), drain 0 only on last step.
//    One barrier per step: staging b_{t+2} (== b_{t-1}) after barrier t is safe
//    since all waves finished compute t-1 before barrier t. --
__global__ __launch_bounds__(256) void gemm0_kernel(
    const unsigned short* __restrict__ Wb, const unsigned short* __restrict__ Xt1,
    const unsigned short* __restrict__ Xi, const float* __restrict__ b0,
    unsigned short* __restrict__ y0t, float* __restrict__ acc0x) {
  __shared__ short sA[3][128 * 32];   // 128 o-rows x 32 k
  __shared__ short sB[3][128 * 32];   // 128 n-rows x 32 k
  __shared__ float ls[256];           // s[128] | ss[128] per local o
  const int lin = blockIdx.x;
  const int xcd = lin & 7;
  const int slot = lin >> 3;            // 0..127
  const int b = xcd * 2 + (slot >> 6);  // 2 batches per XCD
  const int inner = slot & 63;          // 64 blocks per batch
  const int o0 = (inner & 1) * 128;     // 2 o-tiles
  const int n0 = (inner >> 1) * 128;    // 32 n-tiles
  const int tid = threadIdx.x, lane = tid & 63, w = tid >> 6;
  const int wo = w >> 1, wn = w & 1, quad = lane >> 4, l15 = lane & 15;
  const int c0 = tid, c1 = 256 + tid;
  const int r0 = c0 >> 2, j0 = c0 & 3, r1 = c1 >> 2, j1 = c1 & 3;
  const unsigned short* xb = Xt1 + (size_t)(b * 4096 + n0) * 128;
  const unsigned short* xi = Xi + (size_t)(b * 4096 + n0) * 256;
  ls[tid] = 0.f;
  auto STAGE = [&](int h, int kb) {
    gload16(Wb + (size_t)(o0 + r0) * 384 + kb + j0 * 8, &sA[h][c0 * 8]);
    gload16(Wb + (size_t)(o0 + r1) * 384 + kb + j1 * 8, &sA[h][c1 * 8]);
    if (kb < 128) {
      gload16(xb + (size_t)r0 * 128 + kb + j0 * 8, &sB[h][c0 * 8]);
      gload16(xb + (size_t)r1 * 128 + kb + j1 * 8, &sB[h][c1 * 8]);
    } else {
      gload16(xi + (size_t)r0 * 256 + (kb - 128) + j0 * 8, &sB[h][c0 * 8]);
      gload16(xi + (size_t)r1 * 256 + (kb - 128) + j1 * 8, &sB[h][c1 * 8]);
    }
  };
  floatx4 acc[4][4] = {};
  STAGE(0, 0);
  STAGE(1, 32);
  asm volatile("s_waitcnt lgkmcnt(0)" ::: "memory");  // ls-init visible pre-barrier
  int cur = 0, nx = 2;   // nx = (cur+2)%3
  for (int t = 0; t < 12; ++t) {
    if (t < 11) asm volatile("s_waitcnt vmcnt(4)" ::: "memory");
    else        asm volatile("s_waitcnt vmcnt(0)" ::: "memory");
    __builtin_amdgcn_s_barrier();
    __builtin_amdgcn_sched_barrier(0);
    short8 av[4], bv[4];
#pragma unroll
    for (int i = 0; i < 4; ++i)
      av[i] = *(const short8*)(&sA[cur][(wo * 64 + i * 16 + l15) * 32 + quad * 8]);
#pragma unroll
    for (int j = 0; j < 4; ++j)
      bv[j] = *(const short8*)(&sB[cur][(wn * 64 + j * 16 + l15) * 32 + quad * 8]);
#pragma unroll
    for (int i = 0; i < 4; ++i)
#pragma unroll
      for (int j = 0; j < 4; ++j)
        acc[i][j] = __builtin_amdgcn_mfma_f32_16x16x32_bf16(av[i], bv[j], acc[i][j], 0, 0, 0);
    if (t < 10) STAGE(nx, (t + 2) * 32);
    cur = (cur == 2) ? 0 : cur + 1;
    nx = (nx == 2) ? 0 : nx + 1;
  }
#pragma unroll
  for (int i = 0; i < 4; ++i) {
    int obg = o0 + wo * 64 + i * 16 + quad * 4;   // global o
    floatx4 bias = *(const floatx4*)(b0 + obg);
    float ps[4] = {0.f, 0.f, 0.f, 0.f}, pq[4] = {0.f, 0.f, 0.f, 0.f};
#pragma unroll
    for (int j = 0; j < 4; ++j) {
      int n = n0 + wn * 64 + j * 16 + l15;
      ushort4 out;
      out.x = f2bf(acc[i][j][0] + bias[0]);
      out.y = f2bf(acc[i][j][1] + bias[1]);
      out.z = f2bf(acc[i][j][2] + bias[2]);
      out.w = f2bf(acc[i][j][3] + bias[3]);
      *(ushort4*)(y0t + (size_t)(b * 4096 + n) * 256 + obg) = out;
      // stats on the ROUNDED values (self-consistent with what gemm1 reads)
      float q0 = bf2f(out.x), q1 = bf2f(out.y), q2 = bf2f(out.z), q3 = bf2f(out.w);
      ps[0] += q0; ps[1] += q1; ps[2] += q2; ps[3] += q3;
      pq[0] += q0 * q0; pq[1] += q1 * q1; pq[2] += q2 * q2; pq[3] += q3 * q3;
    }
    // reduce across the 16 l15 lanes (same obg within a quad), then one
    // atomic per quad (<=2-way contention: 2 waves share each o-range)
#pragma unroll
    for (int m = 1; m <= 8; m <<= 1) {
#pragma unroll
      for (int u = 0; u < 4; ++u) {
        ps[u] += __shfl_xor(ps[u], m);
        pq[u] += __shfl_xor(pq[u], m);
      }
    }
    if (l15 == 0) {
      int lo = obg - o0;
#pragma unroll
      for (int u = 0; u < 4; ++u) {
        atomicAdd(&ls[lo + u], ps[u]);
        atomicAdd(&ls[128 + lo + u], pq[u]);
      }
    }
  }
  __syncthreads();
  if (tid < 128) {
    atomicAdd(&acc0x[xcd * 512 + o0 + tid], ls[tid]);
    atomicAdd(&acc0x[xcd * 512 + 256 + o0 + tid], ls[128 + tid]);
  }
}

// ---- gemm1 (BN+ReLU fused on A-load, fused stats1, finalize0 folded):
//      y1 = W1b*relu(bn(y0t))^T + b1.  3-buffer counted-vmcnt pipeline;
//      sA via reg-staged XFORM (explicit lgkmcnt(0) before each raw barrier
//      flushes ds_writes), sB via gload16.
//      FIX vs v10: prologue consumes ra(0) via XFORM(0,0) BEFORE LOADRAW(32)
//      refills the ra registers (v10 clobbered ra(0) -> absmax 3.3). ----
__global__ __launch_bounds__(256) void gemm1_kernel(
    const unsigned short* __restrict__ Wb, const unsigned short* __restrict__ y0t,
    const float* __restrict__ acc0x, const float* __restrict__ g0,
    const float* __restrict__ be0, const float* __restrict__ b1,
    float* __restrict__ y1, float* __restrict__ acc1x) {
  __shared__ short sA[3][128 * 32];   // 128 n-rows x 32 k  (BN+ReLU'd x1)
  __shared__ short sB[3][128 * 32];   // 128 o-rows x 32 k
  __shared__ float sst[512];          // scale[256] | offset[256]
  __shared__ float ls[256];           // s[128] | ss[128]
  const int lin = blockIdx.x;
  const int xcd = lin & 7;
  const int slot = lin >> 3;            // 0..63
  const int b = xcd * 2 + (slot >> 5);  // 2 batches per XCD (matches gemm0)
  const int n0 = (slot & 31) * 128;     // 32 n-tiles
  const int tid = threadIdx.x, lane = tid & 63, w = tid >> 6;
  const int wm = w & 1, wo2 = w >> 1, quad = lane >> 4, l15 = lane & 15;
  const unsigned short* W1b = Wb + 98304;
  const int c0 = tid, c1 = 256 + tid;
  const int r0 = c0 >> 2, j0 = c0 & 3, r1 = c1 >> 2, j1 = c1 & 3;
  const unsigned short* yb = y0t + (size_t)(b * 4096 + n0) * 256;
  short8 ra0, ra1;
  auto LOADRAW = [&](int kb) {
    ra0 = *(const short8*)(yb + (size_t)r0 * 256 + kb + j0 * 8);
    ra1 = *(const short8*)(yb + (size_t)r1 * 256 + kb + j1 * 8);
  };
  auto XFORM = [&](int h, int kb) {
    int k0b = kb + j0 * 8, k1b = kb + j1 * 8;
    short8 v0, v1;
#pragma unroll
    for (int u = 0; u < 8; ++u) {
      float t0 = fmaxf(bf2f((unsigned short)ra0[u]) * sst[k0b + u] + sst[256 + k0b + u], 0.f);
      float t1 = fmaxf(bf2f((unsigned short)ra1[u]) * sst[k1b + u] + sst[256 + k1b + u], 0.f);
      v0[u] = (short)f2bf(t0);
      v1[u] = (short)f2bf(t1);
    }
    *(short8*)(&sA[h][c0 * 8]) = v0;
    *(short8*)(&sA[h][c1 * 8]) = v1;
  };
  auto STAGEB = [&](int h, int kb) {
    gload16(W1b + (size_t)r0 * 256 + kb + j0 * 8, &sB[h][c0 * 8]);
    gload16(W1b + (size_t)r1 * 256 + kb + j1 * 8, &sB[h][c1 * 8]);
  };
  LOADRAW(0);
  {  // finalize0 folded: sum per-XCD partials, derive BN scale/offset
    const float inv = 1.0f / 65536.0f;
    float s0 = 0.f, s1 = 0.f;
#pragma unroll
    for (int x = 0; x < 8; ++x) {
      s0 += acc0x[x * 512 + tid];
      s1 += acc0x[x * 512 + 256 + tid];
    }
    float mean = s0 * inv;
    float var = s1 * inv - mean * mean;
    float sc = g0[tid] / sqrtf(var + BN_EPS);
    sst[tid] = sc;
    sst[256 + tid] = be0[tid] - mean * sc;
  }
  ls[tid] = 0.f;
  __syncthreads();                     // sst visible to all (full drain, once)
  STAGEB(0, 0);
  STAGEB(1, 32);
  XFORM(0, 0);                         // consume ra(0) FIRST (v10 bug fix)
  LOADRAW(32);                         // then refill ra for kb=32
  asm volatile("s_waitcnt lgkmcnt(0)" ::: "memory");  // flush XFORM ds_writes
  floatx4 acc[4][4] = {};
  int cur = 0, nx = 2;
  for (int t = 0; t < 8; ++t) {
    if (t < 7) asm volatile("s_waitcnt vmcnt(4)" ::: "memory");
    else       asm volatile("s_waitcnt vmcnt(0)" ::: "memory");
    __builtin_amdgcn_s_barrier();
    __builtin_amdgcn_sched_barrier(0);
    short8 av[4], bv[4];
#pragma unroll
    for (int i = 0; i < 4; ++i)
      av[i] = *(const short8*)(&sA[cur][(wm * 64 + i * 16 + l15) * 32 + quad * 8]);
#pragma unroll
    for (int j = 0; j < 4; ++j)
      bv[j] = *(const short8*)(&sB[cur][(wo2 * 64 + j * 16 + l15) * 32 + quad * 8]);
#pragma unroll
    for (int i = 0; i < 4; ++i)
#pragma unroll
      for (int j = 0; j < 4; ++j)
        acc[i][j] = __builtin_amdgcn_mfma_f32_16x16x32_bf16(av[i], bv[j], acc[i][j], 0, 0, 0);
    if (t < 6) STAGEB(nx, (t + 2) * 32);
    if (t < 7) {
      int nxt1 = (cur == 2) ? 0 : cur + 1;
      XFORM(nxt1, (t + 1) * 32);       // consumes ra(t+1)
      if (t < 6) LOADRAW((t + 2) * 32);
      asm volatile("s_waitcnt lgkmcnt(0)" ::: "memory");  // flush ds_writes
    }
    cur = (cur == 2) ? 0 : cur + 1;
    nx = (nx == 2) ? 0 : nx + 1;
  }
#pragma unroll
  for (int j = 0; j < 4; ++j) {
    int o = wo2 * 64 + j * 16 + l15;
    float bias = b1[o];
    float s = 0.f, q = 0.f;
#pragma unroll
    for (int i = 0; i < 4; ++i) {
      int n = n0 + wm * 64 + i * 16 + quad * 4;
      floatx4 v = acc[i][j] + bias;
      *(floatx4*)(y1 + (size_t)(b * 128 + o) * 4096 + n) = v;
      s += (v[0] + v[1]) + (v[2] + v[3]);
      q += (v[0] * v[0] + v[1] * v[1]) + (v[2] * v[2] + v[3] * v[3]);
    }
    // reduce over the 4 quads (lanes sharing o) then single-lane atomics
    s += __shfl_xor(s, 16); s += __shfl_xor(s, 32);
    q += __shfl_xor(q, 16); q += __shfl_xor(q, 32);
    if (quad == 0) {
      atomicAdd(&ls[o], s);
      atomicAdd(&ls[128 + o], q);
    }
  }
  __syncthreads();
  if (tid < 128) {
    atomicAdd(&acc1x[xcd * 256 + tid], ls[tid]);
    atomicAdd(&acc1x[xcd * 256 + 128 + tid], ls[128 + tid]);
  }
}

// ---------------- bnrelu_f: fp32 in place on d_out, float4/thread ----------------
// finalize1 folded: o is block-uniform; sums per-XCD partials inline.
// grid 8192 x 256
__global__ __launch_bounds__(256) void bnrelu_f_kernel(
    float* __restrict__ y, const float* __restrict__ acc1x,
    const float* __restrict__ g1, const float* __restrict__ be1) {
  size_t i4 = (size_t)blockIdx.x * 256 + threadIdx.x;
  int o = (int)(blockIdx.x >> 2) & 127;   // block covers 1024 floats within one o
  const float inv = 1.0f / 65536.0f;
  float s0 = 0.f, s1 = 0.f;
#pragma unroll
  for (int x = 0; x < 8; ++x) {
    s0 += acc1x[x * 256 + o];
    s1 += acc1x[x * 256 + 128 + o];
  }
  float m = s0 * inv;
  float var = s1 * inv - m * m;
  float sc = g1[o] / sqrtf(var + BN_EPS);
  float bb = be1[o];
  floatx4 v = ((floatx4*)y)[i4];
  floatx4 r;
  r[0] = fmaxf((v[0] - m) * sc + bb, 0.f);
  r[1] = fmaxf((v[1] - m) * sc + bb, 0.f);
  r[2] = fmaxf((v[2] - m) * sc + bb, 0.f);
  r[3] = fmaxf((v[3] - m) * sc + bb, 0.f);
  ((floatx4*)y)[i4] = r;
}

extern "C" void kernel_launch(void* const* d_in, const int* in_sizes, int n_in,
                              void* d_out, int out_size, void* d_ws, size_t ws_size,
                              hipStream_t stream) {
  (void)in_sizes; (void)n_in; (void)out_size; (void)ws_size;
  const float* xyz1    = (const float*)d_in[0];
  const float* xyz2    = (const float*)d_in[1];
  const float* points1 = (const float*)d_in[2];
  const float* points2 = (const float*)d_in[3];
  const float* W0  = (const float*)d_in[4];
  const float* b0  = (const float*)d_in[5];
  const float* g0  = (const float*)d_in[6];
  const float* be0 = (const float*)d_in[7];
  const float* W1  = (const float*)d_in[8];
  const float* b1  = (const float*)d_in[9];
  const float* g1  = (const float*)d_in[10];
  const float* be1 = (const float*)d_in[11];

  char* ws = (char*)d_ws;
  // layout (bytes):
  //   [0,        16K)    acc0x f32[8][512]  } per-XCD stat partials,
  //   [16K,      24K)    acc1x f32[8][256]  } zeroed by one 24576B memset
  //   [1581056,  +256K)  Wb   bf16 (W0b 98304 ++ W1b 32768)
  //   [2M,       10M)    Xt2  bf16 (B,1024,256)
  //   [10M,      26M)    Xt1  bf16 (B,4096,128)
  //   [26M,      58M)    y0t  bf16 (B,4096,256)  -- pre-BN y0 (BN fused in gemm1)
  // Xi bf16 (B,4096,256) = 32 MB lives in d_out; dead before gemm1 writes y1.
  float* acc0x = (float*)(ws + 0);
  float* acc1x = (float*)(ws + 16384);
  unsigned short* Wb  = (unsigned short*)(ws + 1581056);
  unsigned short* Xt2 = (unsigned short*)(ws + 2097152);
  unsigned short* Xt1 = (unsigned short*)(ws + 10485760);
  unsigned short* y0t = (unsigned short*)(ws + 27262976);
  unsigned short* Xi = (unsigned short*)d_out;
  float* y1 = (float*)d_out;

  hipMemsetAsync(acc0x, 0, 24576, stream);
  tcvt_all_kernel<<<3136, 256, 0, stream>>>(points2, Xt2, points1, Xt1, W0, W1, Wb);
  knni_kernel<<<2048, 256, 0, stream>>>(xyz1, xyz2, Xt2, Xi);
  gemm0_kernel<<<1024, 256, 0, stream>>>(Wb, Xt1, Xi, b0, y0t, acc0x);
  gemm1_kernel<<<512, 256, 0, stream>>>(Wb, y0t, acc0x, g0, be0, b1, y1, acc1x);
  bnrelu_f_kernel<<<8192, 256, 0, stream>>>(y1, acc1x, g1, be1);
}

// Round 16
// 214.379 us; speedup vs baseline: 1.0358x; 1.0121x over previous
//
#include <hip/hip_runtime.h>

#define EPS_DIST 1e-10f
#define BN_EPS 1e-5f

typedef short short8 __attribute__((ext_vector_type(8)));
typedef float floatx4 __attribute__((ext_vector_type(4)));

__device__ __forceinline__ unsigned short f2bf(float f) {
  unsigned u = __float_as_uint(f);
  unsigned r = (u + 0x7FFFu + ((u >> 16) & 1u)) >> 16;  // RNE
  return (unsigned short)r;
}
__device__ __forceinline__ float bf2f(unsigned short h) {
  return __uint_as_float(((unsigned)h) << 16);
}

// direct global->LDS async copy, 16B per lane. LDS dest must be
// wave-uniform-base + lane*16 (our staging layouts are exactly that).
__device__ __forceinline__ void gload16(const void* g, void* l) {
  __builtin_amdgcn_global_load_lds(
      (const __attribute__((address_space(1))) unsigned int*)g,
      (__attribute__((address_space(3))) unsigned int*)l, 16, 0, 0);
}

// ------- tcvt_all: 1D grid 3137.
//   id<1024:  points2 fp32[B][256][1024] -> Xt2 bf16[B][1024][256]
//   id<3072:  points1 fp32[B][128][4096] -> Xt1 bf16[B][4096][128]
//   id<3136:  W0 ++ W1 -> Wb bf16
//   id==3136: zero acc0x/acc1x (6144 floats) -- replaces the memset dispatch
__global__ __launch_bounds__(256) void tcvt_all_kernel(
    const float* __restrict__ p2, unsigned short* __restrict__ Xt2,
    const float* __restrict__ p1, unsigned short* __restrict__ Xt1,
    const float* __restrict__ W0, const float* __restrict__ W1,
    unsigned short* __restrict__ Wb, float* __restrict__ accz) {
  const int tid = threadIdx.x;
  const int id = blockIdx.x;
  if (id == 3136) {  // zero 24576 B of stat accumulators
    for (int i = tid; i < 6144; i += 256) accz[i] = 0.f;
    return;
  }
  if (id >= 3072) {  // cvt_w: 64 blocks x 2048 elems = 131072
    int base = (id - 3072) * 2048 + tid;
#pragma unroll
    for (int p = 0; p < 8; ++p) {
      int i = base + p * 256;
      float v = (i < 98304) ? W0[i] : W1[i - 98304];
      Wb[i] = f2bf(v);
    }
    return;
  }
  __shared__ float sm[64][65];
  const float* src; unsigned short* dst; int K, N, n0, k0, b;
  if (id < 1024) {
    src = p2; dst = Xt2; K = 256; N = 1024;
    n0 = (id & 15) * 64; k0 = ((id >> 4) & 3) * 64; b = id >> 6;
  } else {
    int q = id - 1024;
    src = p1; dst = Xt1; K = 128; N = 4096;
    n0 = (q & 63) * 64; k0 = ((q >> 6) & 1) * 64; b = q >> 7;
  }
  const int nl = tid & 63, kq = tid >> 6;
  const float* s = src + ((size_t)b * K + k0) * N + n0;
#pragma unroll
  for (int p = 0; p < 16; ++p) {
    int kl = p * 4 + kq;
    sm[kl][nl] = s[(size_t)kl * N + nl];
  }
  __syncthreads();
#pragma unroll
  for (int p = 0; p < 2; ++p) {
    int c = p * 256 + tid;
    int rn = c >> 3, jj = c & 7;
    short8 v;
#pragma unroll
    for (int u = 0; u < 8; ++u) v[u] = (short)f2bf(sm[jj * 8 + u][rn]);
    *(short8*)(dst + (size_t)(b * N + n0 + rn) * K + k0 + jj * 8) = v;
  }
}

// ---- knni: fused 3-NN + interp of RAW x2 features. (identical to v11) ----
__global__ __launch_bounds__(256) void knni_kernel(
    const float* __restrict__ xyz1, const float* __restrict__ xyz2,
    const unsigned short* __restrict__ Xt2, unsigned short* __restrict__ Xi) {
  __shared__ float4 s2[1024];  // x,y,z,|.|^2
  __shared__ int sidx[96];
  __shared__ float swgt[96];
  const int lin = blockIdx.x;
  const int xcd = lin & 7;
  const int slot = lin >> 3;            // 0..255
  const int b = xcd * 2 + (slot >> 7);  // 2 batches per XCD
  const int qtile = slot & 127;
  const int tid = threadIdx.x;
  const float* x2 = xyz2 + b * 3072;
  for (int j = tid; j < 1024; j += 256) {
    float x = x2[j * 3 + 0], y = x2[j * 3 + 1], z = x2[j * 3 + 2];
    s2[j] = make_float4(x, y, z, (x * x + y * y) + z * z);
  }
  __syncthreads();
  const int q = tid >> 3, sub = tid & 7;
  const int n = qtile * 32 + q;
  const float* p1 = xyz1 + (b * 4096 + n) * 3;
  const float ax = p1[0], ay = p1[1], az = p1[2];
  const float s1 = (ax * ax + ay * ay) + az * az;
  float d0 = 3.4e38f, d1 = 3.4e38f, d2 = 3.4e38f;
  int i0 = 0x7fffffff, i1 = 0x7fffffff, i2 = 0x7fffffff;
#pragma unroll 8
  for (int jj = 0; jj < 128; ++jj) {
    int j = jj * 8 + sub;
    float4 c = s2[j];
    float dot = (ax * c.x + ay * c.y) + az * c.z;
    float d = fmaxf((s1 + c.w) - 2.0f * dot, EPS_DIST);
    bool c0 = d < d0, c1 = d < d1, c2 = d < d2;
    int ni0 = c0 ? j : i0;
    int ni1 = c0 ? i0 : (c1 ? j : i1);
    int ni2 = c1 ? i1 : (c2 ? j : i2);
    float nd0 = fminf(d0, d);
    float nd1 = __builtin_amdgcn_fmed3f(d0, d, d1);
    float nd2 = __builtin_amdgcn_fmed3f(d1, d, d2);
    d0 = nd0; d1 = nd1; d2 = nd2;
    i0 = ni0; i1 = ni1; i2 = ni2;
  }
  // butterfly merge of sorted (d,idx) triples; lexicographic == lax.top_k order
#pragma unroll
  for (int m = 1; m <= 4; m <<= 1) {
    float e0 = __shfl_xor(d0, m), e1 = __shfl_xor(d1, m), e2 = __shfl_xor(d2, m);
    int   f0 = __shfl_xor(i0, m), f1 = __shfl_xor(i1, m), f2 = __shfl_xor(i2, m);
    float A[3] = {d0, d1, d2}, Bv[3] = {e0, e1, e2};
    int   I[3] = {i0, i1, i2}, J[3] = {f0, f1, f2};
    float md[3]; int mi[3];
    int pa = 0, pb = 0;
#pragma unroll
    for (int k = 0; k < 3; ++k) {
      float da = A[pa], db = Bv[pb];
      int ia = I[pa], ib = J[pb];
      bool ta = (da < db) || (da == db && ia < ib);
      md[k] = ta ? da : db; mi[k] = ta ? ia : ib;
      pa += ta ? 1 : 0; pb += ta ? 0 : 1;
    }
    d0 = md[0]; d1 = md[1]; d2 = md[2];
    i0 = mi[0]; i1 = mi[1]; i2 = mi[2];
  }
  if (sub == 0) {
    float w0 = 1.0f / d0, w1 = 1.0f / d1, w2 = 1.0f / d2;
    float s = (w0 + w1) + w2;
    sidx[q * 3 + 0] = i0; sidx[q * 3 + 1] = i1; sidx[q * 3 + 2] = i2;
    swgt[q * 3 + 0] = w0 / s; swgt[q * 3 + 1] = w1 / s; swgt[q * 3 + 2] = w2 / s;
  }
  __syncthreads();
  // ---- phase 2: interp raw x2 feature rows for the block's 32 queries ----
  const int w = tid >> 6, lane = tid & 63;
  const unsigned short* zb = Xt2 + (size_t)b * 1024 * 256;
#pragma unroll
  for (int t = 0; t < 8; ++t) {
    int nl = w * 8 + t;                  // 0..31, wave-uniform
    int nn = qtile * 32 + nl;
    int g0 = sidx[nl * 3 + 0], g1 = sidx[nl * 3 + 1], g2 = sidx[nl * 3 + 2];
    float w0 = swgt[nl * 3 + 0], w1 = swgt[nl * 3 + 1], w2 = swgt[nl * 3 + 2];
    ushort4 r0 = *(const ushort4*)(zb + (size_t)g0 * 256 + lane * 4);
    ushort4 r1 = *(const ushort4*)(zb + (size_t)g1 * 256 + lane * 4);
    ushort4 r2 = *(const ushort4*)(zb + (size_t)g2 * 256 + lane * 4);
    ushort4 o;
    o.x = f2bf(w0 * bf2f(r0.x) + w1 * bf2f(r1.x) + w2 * bf2f(r2.x));
    o.y = f2bf(w0 * bf2f(r0.y) + w1 * bf2f(r1.y) + w2 * bf2f(r2.y));
    o.z = f2bf(w0 * bf2f(r0.z) + w1 * bf2f(r1.z) + w2 * bf2f(r2.z));
    o.w = f2bf(w0 * bf2f(r0.w) + w1 * bf2f(r1.w) + w2 * bf2f(r2.w));
    *(ushort4*)(Xi + ((size_t)b * 4096 + nn) * 256 + lane * 4) = o;
  }
}

// -- gemm0 (+fused stats0): identical to v11. --
__global__ __launch_bounds__(256) void gemm0_kernel(
    const unsigned short* __restrict__ Wb, const unsigned short* __restrict__ Xt1,
    const unsigned short* __restrict__ Xi, const float* __restrict__ b0,
    unsigned short* __restrict__ y0t, float* __restrict__ acc0x) {
  __shared__ short sA[3][128 * 32];   // 128 o-rows x 32 k
  __shared__ short sB[3][128 * 32];   // 128 n-rows x 32 k
  __shared__ float ls[256];           // s[128] | ss[128] per local o
  const int lin = blockIdx.x;
  const int xcd = lin & 7;
  const int slot = lin >> 3;            // 0..127
  const int b = xcd * 2 + (slot >> 6);  // 2 batches per XCD
  const int inner = slot & 63;          // 64 blocks per batch
  const int o0 = (inner & 1) * 128;     // 2 o-tiles
  const int n0 = (inner >> 1) * 128;    // 32 n-tiles
  const int tid = threadIdx.x, lane = tid & 63, w = tid >> 6;
  const int wo = w >> 1, wn = w & 1, quad = lane >> 4, l15 = lane & 15;
  const int c0 = tid, c1 = 256 + tid;
  const int r0 = c0 >> 2, j0 = c0 & 3, r1 = c1 >> 2, j1 = c1 & 3;
  const unsigned short* xb = Xt1 + (size_t)(b * 4096 + n0) * 128;
  const unsigned short* xi = Xi + (size_t)(b * 4096 + n0) * 256;
  ls[tid] = 0.f;
  auto STAGE = [&](int h, int kb) {
    gload16(Wb + (size_t)(o0 + r0) * 384 + kb + j0 * 8, &sA[h][c0 * 8]);
    gload16(Wb + (size_t)(o0 + r1) * 384 + kb + j1 * 8, &sA[h][c1 * 8]);
    if (kb < 128) {
      gload16(xb + (size_t)r0 * 128 + kb + j0 * 8, &sB[h][c0 * 8]);
      gload16(xb + (size_t)r1 * 128 + kb + j1 * 8, &sB[h][c1 * 8]);
    } else {
      gload16(xi + (size_t)r0 * 256 + (kb - 128) + j0 * 8, &sB[h][c0 * 8]);
      gload16(xi + (size_t)r1 * 256 + (kb - 128) + j1 * 8, &sB[h][c1 * 8]);
    }
  };
  floatx4 acc[4][4] = {};
  STAGE(0, 0);
  STAGE(1, 32);
  asm volatile("s_waitcnt lgkmcnt(0)" ::: "memory");  // ls-init visible pre-barrier
  int cur = 0, nx = 2;   // nx = (cur+2)%3
  for (int t = 0; t < 12; ++t) {
    if (t < 11) asm volatile("s_waitcnt vmcnt(4)" ::: "memory");
    else        asm volatile("s_waitcnt vmcnt(0)" ::: "memory");
    __builtin_amdgcn_s_barrier();
    __builtin_amdgcn_sched_barrier(0);
    short8 av[4], bv[4];
#pragma unroll
    for (int i = 0; i < 4; ++i)
      av[i] = *(const short8*)(&sA[cur][(wo * 64 + i * 16 + l15) * 32 + quad * 8]);
#pragma unroll
    for (int j = 0; j < 4; ++j)
      bv[j] = *(const short8*)(&sB[cur][(wn * 64 + j * 16 + l15) * 32 + quad * 8]);
#pragma unroll
    for (int i = 0; i < 4; ++i)
#pragma unroll
      for (int j = 0; j < 4; ++j)
        acc[i][j] = __builtin_amdgcn_mfma_f32_16x16x32_bf16(av[i], bv[j], acc[i][j], 0, 0, 0);
    if (t < 10) STAGE(nx, (t + 2) * 32);
    cur = (cur == 2) ? 0 : cur + 1;
    nx = (nx == 2) ? 0 : nx + 1;
  }
#pragma unroll
  for (int i = 0; i < 4; ++i) {
    int obg = o0 + wo * 64 + i * 16 + quad * 4;   // global o
    floatx4 bias = *(const floatx4*)(b0 + obg);
    float ps[4] = {0.f, 0.f, 0.f, 0.f}, pq[4] = {0.f, 0.f, 0.f, 0.f};
#pragma unroll
    for (int j = 0; j < 4; ++j) {
      int n = n0 + wn * 64 + j * 16 + l15;
      ushort4 out;
      out.x = f2bf(acc[i][j][0] + bias[0]);
      out.y = f2bf(acc[i][j][1] + bias[1]);
      out.z = f2bf(acc[i][j][2] + bias[2]);
      out.w = f2bf(acc[i][j][3] + bias[3]);
      *(ushort4*)(y0t + (size_t)(b * 4096 + n) * 256 + obg) = out;
      // stats on the ROUNDED values (self-consistent with what gemm1 reads)
      float q0 = bf2f(out.x), q1 = bf2f(out.y), q2 = bf2f(out.z), q3 = bf2f(out.w);
      ps[0] += q0; ps[1] += q1; ps[2] += q2; ps[3] += q3;
      pq[0] += q0 * q0; pq[1] += q1 * q1; pq[2] += q2 * q2; pq[3] += q3 * q3;
    }
    // reduce across the 16 l15 lanes (same obg within a quad), then one
    // atomic per quad (<=2-way contention: 2 waves share each o-range)
#pragma unroll
    for (int m = 1; m <= 8; m <<= 1) {
#pragma unroll
      for (int u = 0; u < 4; ++u) {
        ps[u] += __shfl_xor(ps[u], m);
        pq[u] += __shfl_xor(pq[u], m);
      }
    }
    if (l15 == 0) {
      int lo = obg - o0;
#pragma unroll
      for (int u = 0; u < 4; ++u) {
        atomicAdd(&ls[lo + u], ps[u]);
        atomicAdd(&ls[128 + lo + u], pq[u]);
      }
    }
  }
  __syncthreads();
  if (tid < 128) {
    atomicAdd(&acc0x[xcd * 512 + o0 + tid], ls[tid]);
    atomicAdd(&acc0x[xcd * 512 + 256 + o0 + tid], ls[128 + tid]);
  }
}

// ---- gemm1 (BN+ReLU fused on A-load, fused stats1, finalize0 folded):
//      identical to v11 (known-passing). ----
__global__ __launch_bounds__(256) void gemm1_kernel(
    const unsigned short* __restrict__ Wb, const unsigned short* __restrict__ y0t,
    const float* __restrict__ acc0x, const float* __restrict__ g0,
    const float* __restrict__ be0, const float* __restrict__ b1,
    float* __restrict__ y1, float* __restrict__ acc1x) {
  __shared__ short sA[3][128 * 32];   // 128 n-rows x 32 k  (BN+ReLU'd x1)
  __shared__ short sB[3][128 * 32];   // 128 o-rows x 32 k
  __shared__ float sst[512];          // scale[256] | offset[256]
  __shared__ float ls[256];           // s[128] | ss[128]
  const int lin = blockIdx.x;
  const int xcd = lin & 7;
  const int slot = lin >> 3;            // 0..63
  const int b = xcd * 2 + (slot >> 5);  // 2 batches per XCD (matches gemm0)
  const int n0 = (slot & 31) * 128;     // 32 n-tiles
  const int tid = threadIdx.x, lane = tid & 63, w = tid >> 6;
  const int wm = w & 1, wo2 = w >> 1, quad = lane >> 4, l15 = lane & 15;
  const unsigned short* W1b = Wb + 98304;
  const int c0 = tid, c1 = 256 + tid;
  const int r0 = c0 >> 2, j0 = c0 & 3, r1 = c1 >> 2, j1 = c1 & 3;
  const unsigned short* yb = y0t + (size_t)(b * 4096 + n0) * 256;
  short8 ra0, ra1;
  auto LOADRAW = [&](int kb) {
    ra0 = *(const short8*)(yb + (size_t)r0 * 256 + kb + j0 * 8);
    ra1 = *(const short8*)(yb + (size_t)r1 * 256 + kb + j1 * 8);
  };
  auto XFORM = [&](int h, int kb) {
    int k0b = kb + j0 * 8, k1b = kb + j1 * 8;
    short8 v0, v1;
#pragma unroll
    for (int u = 0; u < 8; ++u) {
      float t0 = fmaxf(bf2f((unsigned short)ra0[u]) * sst[k0b + u] + sst[256 + k0b + u], 0.f);
      float t1 = fmaxf(bf2f((unsigned short)ra1[u]) * sst[k1b + u] + sst[256 + k1b + u], 0.f);
      v0[u] = (short)f2bf(t0);
      v1[u] = (short)f2bf(t1);
    }
    *(short8*)(&sA[h][c0 * 8]) = v0;
    *(short8*)(&sA[h][c1 * 8]) = v1;
  };
  auto STAGEB = [&](int h, int kb) {
    gload16(W1b + (size_t)r0 * 256 + kb + j0 * 8, &sB[h][c0 * 8]);
    gload16(W1b + (size_t)r1 * 256 + kb + j1 * 8, &sB[h][c1 * 8]);
  };
  LOADRAW(0);
  {  // finalize0 folded: sum per-XCD partials, derive BN scale/offset
    const float inv = 1.0f / 65536.0f;
    float s0 = 0.f, s1 = 0.f;
#pragma unroll
    for (int x = 0; x < 8; ++x) {
      s0 += acc0x[x * 512 + tid];
      s1 += acc0x[x * 512 + 256 + tid];
    }
    float mean = s0 * inv;
    float var = s1 * inv - mean * mean;
    float sc = g0[tid] / sqrtf(var + BN_EPS);
    sst[tid] = sc;
    sst[256 + tid] = be0[tid] - mean * sc;
  }
  ls[tid] = 0.f;
  __syncthreads();                     // sst visible to all (full drain, once)
  STAGEB(0, 0);
  STAGEB(1, 32);
  XFORM(0, 0);                         // consume ra(0) FIRST (v10 bug fix)
  LOADRAW(32);                         // then refill ra for kb=32
  asm volatile("s_waitcnt lgkmcnt(0)" ::: "memory");  // flush XFORM ds_writes
  floatx4 acc[4][4] = {};
  int cur = 0, nx = 2;
  for (int t = 0; t < 8; ++t) {
    if (t < 7) asm volatile("s_waitcnt vmcnt(4)" ::: "memory");
    else       asm volatile("s_waitcnt vmcnt(0)" ::: "memory");
    __builtin_amdgcn_s_barrier();
    __builtin_amdgcn_sched_barrier(0);
    short8 av[4], bv[4];
#pragma unroll
    for (int i = 0; i < 4; ++i)
      av[i] = *(const short8*)(&sA[cur][(wm * 64 + i * 16 + l15) * 32 + quad * 8]);
#pragma unroll
    for (int j = 0; j < 4; ++j)
      bv[j] = *(const short8*)(&sB[cur][(wo2 * 64 + j * 16 + l15) * 32 + quad * 8]);
#pragma unroll
    for (int i = 0; i < 4; ++i)
#pragma unroll
      for (int j = 0; j < 4; ++j)
        acc[i][j] = __builtin_amdgcn_mfma_f32_16x16x32_bf16(av[i], bv[j], acc[i][j], 0, 0, 0);
    if (t < 6) STAGEB(nx, (t + 2) * 32);
    if (t < 7) {
      int nxt1 = (cur == 2) ? 0 : cur + 1;
      XFORM(nxt1, (t + 1) * 32);       // consumes ra(t+1)
      if (t < 6) LOADRAW((t + 2) * 32);
      asm volatile("s_waitcnt lgkmcnt(0)" ::: "memory");  // flush ds_writes
    }
    cur = (cur == 2) ? 0 : cur + 1;
    nx = (nx == 2) ? 0 : nx + 1;
  }
#pragma unroll
  for (int j = 0; j < 4; ++j) {
    int o = wo2 * 64 + j * 16 + l15;
    float bias = b1[o];
    float s = 0.f, q = 0.f;
#pragma unroll
    for (int i = 0; i < 4; ++i) {
      int n = n0 + wm * 64 + i * 16 + quad * 4;
      floatx4 v = acc[i][j] + bias;
      *(floatx4*)(y1 + (size_t)(b * 128 + o) * 4096 + n) = v;
      s += (v[0] + v[1]) + (v[2] + v[3]);
      q += (v[0] * v[0] + v[1] * v[1]) + (v[2] * v[2] + v[3] * v[3]);
    }
    // reduce over the 4 quads (lanes sharing o) then single-lane atomics
    s += __shfl_xor(s, 16); s += __shfl_xor(s, 32);
    q += __shfl_xor(q, 16); q += __shfl_xor(q, 32);
    if (quad == 0) {
      atomicAdd(&ls[o], s);
      atomicAdd(&ls[128 + o], q);
    }
  }
  __syncthreads();
  if (tid < 128) {
    atomicAdd(&acc1x[xcd * 256 + tid], ls[tid]);
    atomicAdd(&acc1x[xcd * 256 + 128 + tid], ls[128 + tid]);
  }
}

// ---------------- bnrelu_f: fp32 in place on d_out, float4/thread ----------------
// finalize1 folded: o is block-uniform; sums per-XCD partials inline.
// grid 8192 x 256
__global__ __launch_bounds__(256) void bnrelu_f_kernel(
    float* __restrict__ y, const float* __restrict__ acc1x,
    const float* __restrict__ g1, const float* __restrict__ be1) {
  size_t i4 = (size_t)blockIdx.x * 256 + threadIdx.x;
  int o = (int)(blockIdx.x >> 2) & 127;   // block covers 1024 floats within one o
  const float inv = 1.0f / 65536.0f;
  float s0 = 0.f, s1 = 0.f;
#pragma unroll
  for (int x = 0; x < 8; ++x) {
    s0 += acc1x[x * 256 + o];
    s1 += acc1x[x * 256 + 128 + o];
  }
  float m = s0 * inv;
  float var = s1 * inv - m * m;
  float sc = g1[o] / sqrtf(var + BN_EPS);
  float bb = be1[o];
  floatx4 v = ((floatx4*)y)[i4];
  floatx4 r;
  r[0] = fmaxf((v[0] - m) * sc + bb, 0.f);
  r[1] = fmaxf((v[1] - m) * sc + bb, 0.f);
  r[2] = fmaxf((v[2] - m) * sc + bb, 0.f);
  r[3] = fmaxf((v[3] - m) * sc + bb, 0.f);
  ((floatx4*)y)[i4] = r;
}

extern "C" void kernel_launch(void* const* d_in, const int* in_sizes, int n_in,
                              void* d_out, int out_size, void* d_ws, size_t ws_size,
                              hipStream_t stream) {
  (void)in_sizes; (void)n_in; (void)out_size; (void)ws_size;
  const float* xyz1    = (const float*)d_in[0];
  const float* xyz2    = (const float*)d_in[1];
  const float* points1 = (const float*)d_in[2];
  const float* points2 = (const float*)d_in[3];
  const float* W0  = (const float*)d_in[4];
  const float* b0  = (const float*)d_in[5];
  const float* g0  = (const float*)d_in[6];
  const float* be0 = (const float*)d_in[7];
  const float* W1  = (const float*)d_in[8];
  const float* b1  = (const float*)d_in[9];
  const float* g1  = (const float*)d_in[10];
  const float* be1 = (const float*)d_in[11];

  char* ws = (char*)d_ws;
  // layout (bytes):
  //   [0,        16K)    acc0x f32[8][512]  } per-XCD stat partials,
  //   [16K,      24K)    acc1x f32[8][256]  } zeroed by tcvt_all's last block
  //   [1581056,  +256K)  Wb   bf16 (W0b 98304 ++ W1b 32768)
  //   [2M,       10M)    Xt2  bf16 (B,1024,256)
  //   [10M,      26M)    Xt1  bf16 (B,4096,128)
  //   [26M,      58M)    y0t  bf16 (B,4096,256)  -- pre-BN y0 (BN fused in gemm1)
  // Xi bf16 (B,4096,256) = 32 MB lives in d_out; dead before gemm1 writes y1.
  float* acc0x = (float*)(ws + 0);
  float* acc1x = (float*)(ws + 16384);
  unsigned short* Wb  = (unsigned short*)(ws + 1581056);
  unsigned short* Xt2 = (unsigned short*)(ws + 2097152);
  unsigned short* Xt1 = (unsigned short*)(ws + 10485760);
  unsigned short* y0t = (unsigned short*)(ws + 27262976);
  unsigned short* Xi = (unsigned short*)d_out;
  float* y1 = (float*)d_out;

  tcvt_all_kernel<<<3137, 256, 0, stream>>>(points2, Xt2, points1, Xt1, W0, W1, Wb, acc0x);
  knni_kernel<<<2048, 256, 0, stream>>>(xyz1, xyz2, Xt2, Xi);
  gemm0_kernel<<<1024, 256, 0, stream>>>(Wb, Xt1, Xi, b0, y0t, acc0x);
  gemm1_kernel<<<512, 256, 0, stream>>>(Wb, y0t, acc0x, g0, be0, b1, y1, acc1x);
  bnrelu_f_kernel<<<8192, 256, 0, stream>>>(y1, acc1x, g1, be1);
}